// Round 3
// 532.393 us; speedup vs baseline: 1.0147x; 1.0147x over previous
//
#include <hip/hip_runtime.h>

// SNN elementwise state update. Memory-bound: 5 reads + 5 writes of 64 MiB fp32
// = 671 MB traffic -> ~106 us floor at 6.35 TB/s achievable.
// CFG: dt=0.5, kappa_j=0.2, tau_j=8.0, gamma_m=0.1, R_m=5.0, tau_m=10.0,
//      thresh=1.0, t_ref=2.0, tau_tr=20.0
//
// This version vs 118-us-kernel baseline:
//  - grid-stride with capped grid (2048 blocks = 8/CU): more independent
//    16B loads in flight per wave (G11).
//  - non-temporal loads/stores on all 10 streams: zero reuse, keep the
//    read-once/write-once lines from thrashing L2.
//  - clang ext_vector_type for the builtins (HIP float4 is a struct, which
//    __builtin_nontemporal_* rejects); snn_step returns by value since
//    vector elements can't bind to references.

typedef float f32x4 __attribute__((ext_vector_type(4)));

struct Out5 { float v, s, x, j, r; };

__device__ __forceinline__ Out5 snn_step(float I, float v, float x, float j, float r) {
#pragma clang fp contract(off)
    // refractory countdown
    float rc = fmaxf(r - 0.5f, 0.0f);
    // synaptic current: j += (dt/tau_j) * (-kappa_j*j + I); dt/tau_j = 0.0625 exact
    float jn = j + 0.0625f * (-0.2f * j + I);
    // membrane potential, frozen while refractory
    float isr = (rc > 0.0f) ? 1.0f : 0.0f;
    float vn = v + ((1.0f - isr) * 0.05f) * ((-0.1f) * v + 5.0f * jn);
    // threshold -> spike, reset
    float sp = (vn > 1.0f) ? 1.0f : 0.0f;
    Out5 o;
    o.v = vn * (1.0f - sp);
    o.s = sp;
    // low-pass spike trace: x - x/tau_tr + spikes (true division to match ref rounding)
    o.x = x - x / 20.0f + sp;
    o.j = jn;
    o.r = (sp > 0.0f) ? 2.0f : rc;
    return o;
}

__global__ __launch_bounds__(256) void bPC_SNNLayer_65274912965275_kernel(
    const f32x4* __restrict__ Ic,
    const f32x4* __restrict__ v_in,
    const f32x4* __restrict__ x_in,
    const f32x4* __restrict__ j_in,
    const f32x4* __restrict__ r_in,
    f32x4* __restrict__ v_out,
    f32x4* __restrict__ s_out,
    f32x4* __restrict__ x_out,
    f32x4* __restrict__ j_out,
    f32x4* __restrict__ r_out,
    int n4) {
#pragma clang fp contract(off)
    const int stride = gridDim.x * blockDim.x;
    for (int idx = blockIdx.x * blockDim.x + threadIdx.x; idx < n4; idx += stride) {
        f32x4 I = __builtin_nontemporal_load(&Ic[idx]);
        f32x4 v = __builtin_nontemporal_load(&v_in[idx]);
        f32x4 x = __builtin_nontemporal_load(&x_in[idx]);
        f32x4 j = __builtin_nontemporal_load(&j_in[idx]);
        f32x4 r = __builtin_nontemporal_load(&r_in[idx]);

        f32x4 vo, so, xo, jo, ro;
#pragma unroll
        for (int k = 0; k < 4; ++k) {
            Out5 o = snn_step(I[k], v[k], x[k], j[k], r[k]);
            vo[k] = o.v;
            so[k] = o.s;
            xo[k] = o.x;
            jo[k] = o.j;
            ro[k] = o.r;
        }

        __builtin_nontemporal_store(vo, &v_out[idx]);
        __builtin_nontemporal_store(so, &s_out[idx]);
        __builtin_nontemporal_store(xo, &x_out[idx]);
        __builtin_nontemporal_store(jo, &j_out[idx]);
        __builtin_nontemporal_store(ro, &r_out[idx]);
    }
}

extern "C" void kernel_launch(void* const* d_in, const int* in_sizes, int n_in,
                              void* d_out, int out_size, void* d_ws, size_t ws_size,
                              hipStream_t stream) {
    // setup_inputs order: total_input_current, v, x, j, ref_count
    const float* I = (const float*)d_in[0];
    const float* v = (const float*)d_in[1];
    const float* x = (const float*)d_in[2];
    const float* j = (const float*)d_in[3];
    const float* r = (const float*)d_in[4];

    const int n = in_sizes[0];       // 4096*4096 = 16777216, divisible by 4
    const int n4 = n / 4;

    float* out = (float*)d_out;      // (v, s, x, j, ref_count) concatenated
    float* vo = out;
    float* so = out + (size_t)n;
    float* xo = out + 2 * (size_t)n;
    float* jo = out + 3 * (size_t)n;
    float* ro = out + 4 * (size_t)n;

    const int block = 256;
    // G11: memory-bound -> cap grid at ~8 blocks/CU (256 CU) and grid-stride.
    int grid = (n4 + block - 1) / block;
    if (grid > 2048) grid = 2048;
    bPC_SNNLayer_65274912965275_kernel<<<grid, block, 0, stream>>>(
        (const f32x4*)I, (const f32x4*)v, (const f32x4*)x,
        (const f32x4*)j, (const f32x4*)r,
        (f32x4*)vo, (f32x4*)so, (f32x4*)xo, (f32x4*)jo, (f32x4*)ro, n4);
}